// Round 14
// baseline (32.878 us; speedup 1.0000x reference)
//
#include <hip/hip_runtime.h>

// BKT: B=4096 students, T=512 timesteps, K=2048 skills.
// R14: bitmap replay. R13 probe measured R10's walk+replay at ~6.4us of the
// 15.2us total -- dependent LDS pointer-chase latency. This version makes
// every replay read INDEPENDENT:
//  - bmap[16][256] word-major occurrence bitmaps (bucket = sk & 255, 8
//    skills/bucket). Build: 1 atomicOr per timestep. Query: read words
//    0..t>>5 (avg ~8, pipelined, bank = bucket&31 ~ 2-way random = free),
//    iterate set bits ascending = time order for free; aliens filtered by
//    sk_s[j] u16 read. No caps -> no overflow path, no straggler tail.
//  - responses as a 64B bitset built with one __ballot per wave per u
//    (wave lanes cover a contiguous 64-aligned t window).
//  - conditional t/g/s gathers on first match (R11: unconditional hurts);
//    k0 gather hoisted (R10 baseline).
// LDS 17.1KB -> 8 blocks/CU = 32 waves. Two barriers, unchanged.

#define BKT_B 4096
#define BKT_T 512
#define BKT_K 2048
#define BLK   256
#define TPT   (BKT_T / BLK)   // 2 timesteps per thread
#define NB    256             // bitmap buckets
#define NW    (BKT_T / 32)    // 16 words per bucket

__device__ __forceinline__ float bkt_update(float p, int rbit, float ss,
                                            float gg, float tt) {
  float num, den;
  if (rbit) {                // correct response
    num = p * (1.0f - ss);
    den = num + (1.0f - p) * gg;
  } else {                   // incorrect response
    num = p * ss;
    den = num + (1.0f - p) * (1.0f - gg);
  }
  const float q = num / den; // Bayesian posterior
  return q + (1.0f - q) * tt;// learning transition
}

__global__ __launch_bounds__(BLK) void bkt_kernel(
    const int* __restrict__ skills,
    const float* __restrict__ resp,
    const float* __restrict__ k0,
    const float* __restrict__ tp,
    const float* __restrict__ gp,
    const float* __restrict__ sp,
    float* __restrict__ out) {
  __shared__ unsigned int   bmap_s[NW][NB];  // 16KB word-major bitmaps
  __shared__ unsigned short sk_s[BKT_T];     // 1KB alien filter
  __shared__ unsigned int   resp_s[NW];      // 64B response bitset

  const int b = blockIdx.x;
  const int base = b * BKT_T;
  const int tid = threadIdx.x;

  // coalesced row loads; k0 gather issued early (latency hides under build)
  int   sk[TPT];
  float rr[TPT];
  float k0v[TPT];
#pragma unroll
  for (int u = 0; u < TPT; ++u) {
    const int t = tid + u * BLK;
    sk[u] = skills[base + t];
    rr[u] = resp[base + t];
  }
#pragma unroll
  for (int u = 0; u < TPT; ++u)
    k0v[u] = k0[sk[u]];

  // zero bitmaps: 16KB = 1024 int4 = 4 per thread
  {
    int4* z = (int4*)&bmap_s[0][0];
#pragma unroll
    for (int i = 0; i < 4; ++i)
      z[tid + i * BLK] = make_int4(0, 0, 0, 0);
  }

  // skill row + response bitset (ballot: wave covers contiguous 64 t's)
#pragma unroll
  for (int u = 0; u < TPT; ++u) {
    const int t = tid + u * BLK;
    sk_s[t] = (unsigned short)sk[u];
    const unsigned long long m = __ballot(rr[u] > 0.5f);
    if ((tid & 63) == 0) {
      const int w0 = t >> 5;                 // lane0: t is 64-aligned
      resp_s[w0]     = (unsigned int)(m & 0xffffffffu);
      resp_s[w0 + 1] = (unsigned int)(m >> 32);
    }
  }
  __syncthreads();

  // build occurrence bitmaps
#pragma unroll
  for (int u = 0; u < TPT; ++u) {
    const int t = tid + u * BLK;
    atomicOr(&bmap_s[t >> 5][sk[u] & (NB - 1)], 1u << (t & 31));
  }
  __syncthreads();

  // query: scan own bucket's words below t (independent reads, pipelined)
#pragma unroll
  for (int u = 0; u < TPT; ++u) {
    const int t = tid + u * BLK;
    const int s_ = sk[u];
    const int bucket = s_ & (NB - 1);
    const int wt = t >> 5;

    float p = k0v[u];
    float ss = 0.f, gg = 0.f, tt = 0.f;
    bool have = false;

    for (int w = 0; w <= wt; ++w) {
      unsigned int bits = bmap_s[w][bucket];
      if (w == wt) bits &= (1u << (t & 31)) - 1u;   // strictly below t
      while (bits) {
        const int j = (w << 5) + __builtin_ctz(bits);
        bits &= bits - 1;
        if (sk_s[j] == (unsigned short)s_) {        // reject bucket aliens
          if (!have) {                              // lazy param gather
            ss = sp[s_]; gg = gp[s_]; tt = tp[s_];
            have = true;
          }
          const unsigned int rw = resp_s[j >> 5];
          p = bkt_update(p, (int)((rw >> (j & 31)) & 1u), ss, gg, tt);
        }
      }
    }

    out[base + t] = p;                  // emit pre-update mastery
  }
}

extern "C" void kernel_launch(void* const* d_in, const int* in_sizes, int n_in,
                              void* d_out, int out_size, void* d_ws, size_t ws_size,
                              hipStream_t stream) {
  const int*   skills = (const int*)d_in[0];
  const float* resp   = (const float*)d_in[1];
  const float* k0     = (const float*)d_in[2];
  const float* tp     = (const float*)d_in[3];
  const float* gp     = (const float*)d_in[4];
  const float* sp     = (const float*)d_in[5];
  float* out = (float*)d_out;

  bkt_kernel<<<BKT_B, BLK, 0, stream>>>(skills, resp, k0, tp, gp, sp, out);
}

// Round 15
// 13.990 us; speedup vs baseline: 2.3501x; 2.3501x over previous
//
#include <hip/hip_runtime.h>
#include <limits.h>

// BKT: B=4096 students, T=512 timesteps, K=2048 skills.
// R15 = R10 structure with the walk's exposed latency halved:
//  1. dual-chain interleaved walk: u=0 and u=1 chains advance in ONE loop
//     (two independent chain pointers -> 2 ds_reads in flight/iteration;
//     exposure ~ max(len0,len1) instead of len0+len1).
//  2. min1+min2 captured during the walk -> rank<=2 replaying lanes (~97%)
//     need no rescan; rescan loop only for rank>=3 (~0.3% of lanes).
//  3. direct-mapped 2048-entry head table: no hash aliens (shorter chains,
//     no per-hop filter). node = [10]=resp bit, [9:0]=prev ptr.
// k0 hoisted; t/g/s lazy (R11: unconditional hoist hurts); 2 barriers.
// LDS 10KB -> 8 blocks/CU; launch_bounds(256,8) pins VGPR<=64 (32 waves).
// R14 lesson: divergent data-dependent loop nests (bitmap scan) cost more
// than the dependent-hop latency they remove.

#define BKT_B 4096
#define BKT_T 512
#define BKT_K 2048
#define BLK   256
#define PTR_END 0x3FF

__device__ __forceinline__ float bkt_update(float p, int rbit, float ss,
                                            float gg, float tt) {
  float num, den;
  if (rbit) {                // correct response
    num = p * (1.0f - ss);
    den = num + (1.0f - p) * gg;
  } else {                   // incorrect response
    num = p * ss;
    den = num + (1.0f - p) * (1.0f - gg);
  }
  const float q = num / den; // Bayesian posterior
  return q + (1.0f - q) * tt;// learning transition
}

__global__ __launch_bounds__(BLK, 8) void bkt_kernel(
    const int* __restrict__ skills,
    const float* __restrict__ resp,
    const float* __restrict__ k0,
    const float* __restrict__ tp,
    const float* __restrict__ gp,
    const float* __restrict__ sp,
    float* __restrict__ out) {
  __shared__ int head_s[BKT_K];  // 8KB direct-mapped: last arrival, -1 empty
  __shared__ int node_s[BKT_T];  // 2KB packed {resp bit, prev ptr}

  const int b = blockIdx.x;
  const int base = b * BKT_T;
  const int tid = threadIdx.x;
  const int t0 = tid;
  const int t1 = tid + BLK;

  // coalesced row loads; k0 gathers issued early (hide under init/build)
  const int   sk0 = skills[base + t0];
  const int   sk1 = skills[base + t1];
  const float rr0 = resp[base + t0];
  const float rr1 = resp[base + t1];
  const float k00 = k0[sk0];
  const float k01 = k0[sk1];

  // head init: 2048 ints = two int4 stores per thread
  {
    int4* h4 = (int4*)head_s;
    h4[tid] = make_int4(-1, -1, -1, -1);
    h4[tid + BLK] = make_int4(-1, -1, -1, -1);
  }
  __syncthreads();

  // build per-skill linked lists (arrival order arbitrary)
  {
    const int old0 = atomicExch(&head_s[sk0], t0);
    node_s[t0] = ((old0 < 0) ? PTR_END : old0) | ((rr0 > 0.5f ? 1 : 0) << 10);
    const int old1 = atomicExch(&head_s[sk1], t1);
    node_s[t1] = ((old1 < 0) ? PTR_END : old1) | ((rr1 > 0.5f ? 1 : 0) << 10);
  }
  __syncthreads();

  // dual-chain interleaved walk: both u's chains advance per iteration
  const int head0 = head_s[sk0];
  const int head1 = head_s[sk1];
  int j0 = head0, j1 = head1;
  int rank0 = 0, rank1 = 0;
  int a0 = INT_MAX, b0 = INT_MAX, an0 = 0, bn0 = 0;  // min1/min2 (u=0)
  int a1 = INT_MAX, b1 = INT_MAX, an1 = 0, bn1 = 0;  // min1/min2 (u=1)
  while ((j0 >= 0) || (j1 >= 0)) {
    if (j0 >= 0) {
      const int nd = node_s[j0];
      if (j0 < t0) {
        ++rank0;
        if (j0 < a0)      { b0 = a0; bn0 = an0; a0 = j0; an0 = nd; }
        else if (j0 < b0) { b0 = j0; bn0 = nd; }
      }
      const int nx = nd & PTR_END;
      j0 = (nx == PTR_END) ? -1 : nx;
    }
    if (j1 >= 0) {
      const int nd = node_s[j1];
      if (j1 < t1) {
        ++rank1;
        if (j1 < a1)      { b1 = a1; bn1 = an1; a1 = j1; an1 = nd; }
        else if (j1 < b1) { b1 = j1; bn1 = nd; }
      }
      const int nx = nd & PTR_END;
      j1 = (nx == PTR_END) ? -1 : nx;
    }
  }

  // ---- u = 0 replay ----
  float p0 = k00;
  if (rank0 > 0) {
    const float ss = sp[sk0];
    const float gg = gp[sk0];
    const float tt = tp[sk0];
    p0 = bkt_update(p0, (an0 >> 10) & 1, ss, gg, tt);
    if (rank0 > 1) {
      p0 = bkt_update(p0, (bn0 >> 10) & 1, ss, gg, tt);
      int cur = b0;
      for (int rd = 2; rd < rank0; ++rd) {   // rank>=3 only (~0.3% lanes)
        int best = INT_MAX, bestnode = 0;
        for (int j = head0; j >= 0; ) {
          const int nd = node_s[j];
          if (j < t0 && j > cur && j < best) { best = j; bestnode = nd; }
          const int nx = nd & PTR_END;
          j = (nx == PTR_END) ? -1 : nx;
        }
        p0 = bkt_update(p0, (bestnode >> 10) & 1, ss, gg, tt);
        cur = best;
      }
    }
  }
  out[base + t0] = p0;                 // emit pre-update mastery

  // ---- u = 1 replay ----
  float p1 = k01;
  if (rank1 > 0) {
    const float ss = sp[sk1];
    const float gg = gp[sk1];
    const float tt = tp[sk1];
    p1 = bkt_update(p1, (an1 >> 10) & 1, ss, gg, tt);
    if (rank1 > 1) {
      p1 = bkt_update(p1, (bn1 >> 10) & 1, ss, gg, tt);
      int cur = b1;
      for (int rd = 2; rd < rank1; ++rd) {
        int best = INT_MAX, bestnode = 0;
        for (int j = head1; j >= 0; ) {
          const int nd = node_s[j];
          if (j < t1 && j > cur && j < best) { best = j; bestnode = nd; }
          const int nx = nd & PTR_END;
          j = (nx == PTR_END) ? -1 : nx;
        }
        p1 = bkt_update(p1, (bestnode >> 10) & 1, ss, gg, tt);
        cur = best;
      }
    }
  }
  out[base + t1] = p1;                 // emit pre-update mastery
}

extern "C" void kernel_launch(void* const* d_in, const int* in_sizes, int n_in,
                              void* d_out, int out_size, void* d_ws, size_t ws_size,
                              hipStream_t stream) {
  const int*   skills = (const int*)d_in[0];
  const float* resp   = (const float*)d_in[1];
  const float* k0     = (const float*)d_in[2];
  const float* tp     = (const float*)d_in[3];
  const float* gp     = (const float*)d_in[4];
  const float* sp     = (const float*)d_in[5];
  float* out = (float*)d_out;

  bkt_kernel<<<BKT_B, BLK, 0, stream>>>(skills, resp, k0, tp, gp, sp, out);
}